// Round 4
// baseline (244.061 us; speedup 1.0000x reference)
//
#include <hip/hip_runtime.h>

#define LPC_N 32
#define LPC_EPS 1e-5f
#define NREG 11                       // lags 0..10: reg-resident (0 -> E only)
#define NLDS (LPC_N + 1 - NREG)       // lags 11..32: per-wave LDS (22 vals)

// R1/R3 post-mortem: VGPR_Count=36 + occupancy pinned at 5 waves/SIMD + zero
// scratch traffic => the 65-float working set was AGPR-shadowed (unified RF:
// ~36 VGPR + ~64 AGPR = 100/thread). Every array touch paid a
// v_accvgpr_read/write (VALU-time ~2x the raw math) and launch_bounds was
// silently violated. Fix: shrink the HONEST live set below the cap so the
// allocator never reaches for AGPRs:
//   - lp[32] + ac[1..10] (hot lags, used 23..32x) in VGPRs (~55 live incl.
//     temps, under the 73-reg cap of __launch_bounds__(256,7)).
//   - lags 11..32 in per-wave LDS, lag-major [lag][64 lanes]: bank = lane%32
//     -> 2-way = conflict-free; adjacent lags 64 dwords apart -> ds_read2
//     mergeable; reads issue on the DS pipe, off the VALU critical path.
// LDS 22 KB/block -> 7 blocks/CU = 28 waves/CU (87% occupancy).
__global__ __launch_bounds__(256, 7) void levinson_kernel(
    const float* __restrict__ pAC,   // [N+1, T]
    float* __restrict__ out,         // [N, T]
    int T)
{
    __shared__ float smem[4 * NLDS * 64];   // 22528 B/block, per-wave chunks

    const int tid  = threadIdx.x;
    const int lane = tid & 63;
    const int wv   = tid >> 6;
    const int t    = blockIdx.x * blockDim.x + tid;
    if (t >= T) return;

    float* wbuf = smem + wv * (NLDS * 64);

    // Stage cold lags into per-wave LDS. Wave-private -> no __syncthreads;
    // hi[] temps are transient (lp not yet live). 22+11 global loads issue
    // back-to-back for full MLP.
    {
        float hi[NLDS];
#pragma unroll
        for (int k = 0; k < NLDS; ++k)
            hi[k] = pAC[(size_t)(NREG + k) * T + t];
#pragma unroll
        for (int k = 0; k < NLDS; ++k)
            wbuf[k * 64 + lane] = hi[k];
    }

    // Hot lags -> registers (coalesced dword loads, 256 B/wave/row).
    float ac[NREG];                   // ac[0] only seeds E (dead after)
#pragma unroll
    for (int k = 0; k < NREG; ++k)
        ac[k] = pAC[(size_t)k * T + t];

    // Fully unrolled => m is a compile-time constant: folds to a VGPR read
    // or a ds_read_b32 with an immediate offset.
    auto AC = [&](int m) -> float {
        return (m < NREG) ? ac[m] : wbuf[(m - NREG) * 64 + lane];
    };

    float lp[LPC_N];
    float E = ac[0];

#pragma unroll
    for (int i = 0; i < LPC_N; ++i) {
        // rcp issued first: latency hides under the dot product.
        float invE = __builtin_amdgcn_rcpf(E);

        // acc = ac[i+1] + sum_{j<i} lp[j]*ac[i-j], two independent FMA chains.
        float s0 = AC(i + 1);
        float s1 = 0.0f;
#pragma unroll
        for (int j = 0; j + 1 < i; j += 2) {
            s0 += lp[j]     * AC(i - j);
            s1 += lp[j + 1] * AC(i - j - 1);
        }
        if (i & 1) {                    // leftover j = i-1 when i is odd
            s0 += lp[i - 1] * ac[1];
        }
        float acc = s0 + s1;

        float ki = acc * invE;
        float c  = fmaxf(1.0f - ki * ki, LPC_EPS);
        E *= c;

        // lp[j] = lp[j] - ki*lp[i-1-j] from OLD lp: pairwise swap update.
#pragma unroll
        for (int j = 0; j < i - 1 - j; ++j) {
            float a = lp[j];
            float b = lp[i - 1 - j];
            lp[j]         = a - ki * b;
            lp[i - 1 - j] = b - ki * a;
        }
        if (i & 1) {
            int m = (i - 1) >> 1;       // self-paired middle element
            lp[m] = lp[m] - ki * lp[m];
        }
        lp[i] = -ki;
    }

    // Nontemporal coalesced stores: write-once/never-read, keep out of LLC.
#pragma unroll
    for (int i = 0; i < LPC_N; ++i) {
        __builtin_nontemporal_store(lp[i], &out[(size_t)i * T + t]);
    }
}

extern "C" void kernel_launch(void* const* d_in, const int* in_sizes, int n_in,
                              void* d_out, int out_size, void* d_ws, size_t ws_size,
                              hipStream_t stream)
{
    const float* pAC = (const float*)d_in[0];
    float* out = (float*)d_out;
    int T = in_sizes[0] / (LPC_N + 1);   // 1048576

    int block = 256;
    int grid = (T + block - 1) / block;  // 4096 blocks
    levinson_kernel<<<grid, block, 0, stream>>>(pAC, out, T);
}